// Round 5
// baseline (371.805 us; speedup 1.0000x reference)
//
#include <hip/hip_runtime.h>
#include <hip/hip_fp16.h>
#include <math.h>

// 2-layer GAT. N=50000, E=800000 (+N self loops), F=128, H=8, C=32, NCLS=16.
// R21: R20 fusion REVERTED (butterfly = 96 ds_bpermute serial chain, +1200
// cyc/wave, agg1 97us). K5 split restored. agg1 v4: CHANNEL-SLICED across
// XCDs -- FETCH=221MB == h1(25.6MB) x 8 XCD L2s (random rows, 25.6MB >> 4MiB
// L2). New: wave per (dst,head); head = blockIdx&7 rides the round-robin
// block->XCD map so each XCD touches only h1[:,head] = 3.2MB -> L2-RESIDENT.
// 16 lanes x 64B slice, 4 edge-slots, 2 rounds unrolled (8 gathers in
// flight), no LDS, ~30 VGPR -> 32 waves/CU. Weights recomputed per head
// (1 exp/edge/slice). Predicted: FETCH -> ~70MB, agg1 73 -> ~50us.
//   K1 histW | K2 scanAB+gemm1 | K3 scatter3+rowfin | K4 agg1 | K5 gemm2 | K6 agg2

#define NC    128          // edge chunks
#define NBK   256          // hist/scatter blocks = NC * 2 halves
#define NBINS 50000
#define HBINS 25000        // bins per half
#define NWH   12500        // packed u32 words per half (2 bins each)

typedef _Float16 f16x8 __attribute__((ext_vector_type(8)));
typedef _Float16 f16x4 __attribute__((ext_vector_type(4)));
typedef float    f32x4 __attribute__((ext_vector_type(4)));

__device__ __forceinline__ float lrelu(float v){ return v > 0.f ? v : 0.2f*v; }

// ---------------- K1: hist (packed u16, chunk x half) + weight prep ----------------
__global__ __launch_bounds__(256) void k_histW(const int* __restrict__ dstv,
    unsigned int* __restrict__ partial, int E, int Etot, int chunk,
    const float* __restrict__ W1, _Float16* __restrict__ W1t,
    const float* __restrict__ W2, _Float16* __restrict__ W2t)
{
  int b = blockIdx.x, t = threadIdx.x;
  if (b >= NBK){
    int b2 = b - NBK;
    if (b2 < 128){
      W1t[t*128 + b2] = (_Float16)W1[b2*256 + t];
    } else {
      for (int i=t; i<4096; i+=256){ int k=i&255, j=i>>8; W2t[j*256+k] = (_Float16)W2[k*16+j]; }
    }
    return;
  }
  __shared__ unsigned int cnt[NWH];         // 50 KB -> 2 blocks/CU
  int c = b >> 1, half = b & 1, lo = half*HBINS;
  for (int i=t; i<NWH; i+=256) cnt[i] = 0u;
  __syncthreads();
  int e0 = c*chunk, e1 = e0+chunk; if (e1 > Etot) e1 = Etot;
  int e = e0 + t;
  for (; e + 768 < e1; e += 1024){
    int ea=e, eb=e+256, ec=e+512, ed=e+768;
    int d0 = (ea<E)?dstv[ea]:(ea-E);
    int d1 = (eb<E)?dstv[eb]:(eb-E);
    int d2 = (ec<E)?dstv[ec]:(ec-E);
    int d3 = (ed<E)?dstv[ed]:(ed-E);
    int r0=d0-lo, r1=d1-lo, r2=d2-lo, r3=d3-lo;
    if (r0>=0 && r0<HBINS) atomicAdd(&cnt[r0>>1], (r0&1)?65536u:1u);
    if (r1>=0 && r1<HBINS) atomicAdd(&cnt[r1>>1], (r1&1)?65536u:1u);
    if (r2>=0 && r2<HBINS) atomicAdd(&cnt[r2>>1], (r2&1)?65536u:1u);
    if (r3>=0 && r3<HBINS) atomicAdd(&cnt[r3>>1], (r3&1)?65536u:1u);
  }
  for (; e < e1; e += 256){
    int d = (e<E)?dstv[e]:(e-E);
    int r = d - lo;
    if (r>=0 && r<HBINS) atomicAdd(&cnt[r>>1], (r&1)?65536u:1u);
  }
  __syncthreads();
  unsigned int* dp = partial + (size_t)c*HBINS + (size_t)half*NWH;
  for (int i=t; i<NWH; i+=256) dp[i] = cnt[i];
}

// ---------------- K2: scanAB (blocks 0..SB-1, batched prefetch) + GEMM1 tiles ----------------
__global__ __launch_bounds__(256) void k_g1scan(const float* __restrict__ x,
    const _Float16* __restrict__ W1t, const float* __restrict__ as1,
    const float* __restrict__ ad1, _Float16* __restrict__ h1,
    float* __restrict__ a_src1, float* __restrict__ a_dst1,
    unsigned long long* __restrict__ partial, int* __restrict__ rowptr,
    int* __restrict__ bsum, int N, int SB)
{
  __shared__ char smem[33792];
  int t = threadIdx.x;
  int b = blockIdx.x;

  if (b < SB){
    // ---- scanAB with explicit 16-deep load batching (breaks latency chain) ----
    int* lds = (int*)smem;
    int base = b*1024 + t*4;
    int r0=0, r1=0, r2=0, r3=0;
    if (base < N){
      unsigned long long* P = partial + (base >> 2);
      for (int cc0=0; cc0<NC; cc0+=16){
        unsigned long long v[16];
        #pragma unroll
        for (int j=0;j<16;++j) v[j] = P[(size_t)(cc0+j)*12500];   // 16 loads in flight
        #pragma unroll
        for (int j=0;j<16;++j){
          unsigned long long pref =  (unsigned long long)(r0 & 0xffff)
            | ((unsigned long long)(r1 & 0xffff) << 16)
            | ((unsigned long long)(r2 & 0xffff) << 32)
            | ((unsigned long long)(r3 & 0xffff) << 48);
          P[(size_t)(cc0+j)*12500] = pref;
          r0 += (int)( v[j]        & 0xffff);
          r1 += (int)((v[j] >> 16) & 0xffff);
          r2 += (int)((v[j] >> 32) & 0xffff);
          r3 += (int)((v[j] >> 48) & 0xffff);
        }
      }
    }
    int tot = r0+r1+r2+r3;
    lds[t] = tot; __syncthreads();
    for (int off=1; off<256; off<<=1){
      int add = (t>=off)?lds[t-off]:0;
      __syncthreads();
      lds[t] += add;
      __syncthreads();
    }
    int excl = lds[t] - tot;
    if (t==255) bsum[b] = lds[t];
    int run = excl;
    if (base+0<N){ rowptr[base+0]=run; run+=r0; }
    if (base+1<N){ rowptr[base+1]=run; run+=r1; }
    if (base+2<N){ rowptr[base+2]=run; run+=r2; }
    if (base+3<N){ rowptr[base+3]=run; }
    return;
  }

  // ---- GEMM1 (MFMA): h1 = x @ W1 -> fp16, + a_src1/a_dst1 ----
  _Float16* As = (_Float16*)smem;           // [64 rows][136 halves] (272 B stride)
  int n0 = (b - SB)*64;

  #pragma unroll
  for (int it=0; it<8; ++it){
    int c = it*256 + t;
    int row = c >> 5;
    int c4  = c & 31;
    int gr = n0 + row; if (gr > N-1) gr = N-1;
    float4 v = *(const float4*)(x + (size_t)gr*128 + c4*4);
    _Float16* dp = As + row*136 + c4*4;
    dp[0]=(_Float16)v.x; dp[1]=(_Float16)v.y; dp[2]=(_Float16)v.z; dp[3]=(_Float16)v.w;
  }
  __syncthreads();

  int wv = t>>6, lane = t&63;
  int m = lane&15, q = lane>>4;
  int r0w = wv*16;

  f16x8 afr[4];
  #pragma unroll
  for (int ks=0; ks<4; ++ks)
    afr[ks] = *(const f16x8*)((const char*)As + (r0w+m)*272 + ks*64 + q*16);

  f32x4 acc[16];
  #pragma unroll
  for (int ct=0; ct<16; ++ct) acc[ct] = (f32x4){0.f,0.f,0.f,0.f};

  const char* bbase = (const char*)W1t;
  #pragma unroll
  for (int ct=0; ct<16; ++ct){
    const char* bp = bbase + (ct*16 + m)*256 + q*16;
    f16x8 b0 = *(const f16x8*)(bp);
    f16x8 b1 = *(const f16x8*)(bp+64);
    f16x8 b2 = *(const f16x8*)(bp+128);
    f16x8 b3 = *(const f16x8*)(bp+192);
    acc[ct] = __builtin_amdgcn_mfma_f32_16x16x32_f16(afr[0], b0, acc[ct],0,0,0);
    acc[ct] = __builtin_amdgcn_mfma_f32_16x16x32_f16(afr[1], b1, acc[ct],0,0,0);
    acc[ct] = __builtin_amdgcn_mfma_f32_16x16x32_f16(afr[2], b2, acc[ct],0,0,0);
    acc[ct] = __builtin_amdgcn_mfma_f32_16x16x32_f16(afr[3], b3, acc[ct],0,0,0);
  }
  __syncthreads();

  _Float16* Hs = (_Float16*)smem;           // [64][264] halves, 528B stride
  #pragma unroll
  for (int ct=0; ct<16; ++ct){
    #pragma unroll
    for (int r=0; r<4; ++r)
      Hs[(size_t)(r0w + q*4 + r)*264 + ct*16 + m] = (_Float16)acc[ct][r];
  }
  __syncthreads();

  for (int r=0; r<16; ++r){
    int grow = n0 + r0w + r;
    if (grow < N){
      uint2 v = *(const uint2*)((const char*)Hs + (size_t)(r0w+r)*528 + lane*8);
      *(uint2*)((char*)h1 + (size_t)grow*512 + lane*8) = v;
    }
  }

  #pragma unroll
  for (int p=t; p<512; p+=256){
    int row = p>>3, hd = p&7;
    int grow = n0 + row;
    if (grow < N){
      const _Float16* hr = Hs + (size_t)row*264 + hd*32;
      float sa=0.f, sd=0.f;
      #pragma unroll
      for (int c=0; c<32; ++c){
        float hv = (float)hr[c];
        sa += hv * as1[hd*32+c];
        sd += hv * ad1[hd*32+c];
      }
      a_src1[(size_t)grow*8+hd] = sa;
      a_dst1[(size_t)grow*8+hd] = sd;
    }
  }
}

// ---------------- K3: scatter (chunk x half, LDS u16 cursors) + rowfin finalize ----------------
__global__ __launch_bounds__(256) void k_scatter3(const int* __restrict__ srcv,
    const int* __restrict__ dstv, const int* __restrict__ rowptr,
    const unsigned short* __restrict__ pu, const int* __restrict__ bsum,
    int* __restrict__ csr_src, int* __restrict__ rowfin,
    int E, int Etot, int chunk, int SB, int N)
{
  __shared__ unsigned int cur[NWH];         // 50 KB -> 2 blocks/CU
  __shared__ int bpre[64];
  int b = blockIdx.x, t = threadIdx.x;
  int c = b >> 1, half = b & 1, lo = half*HBINS;
  for (int i=t; i<NWH; i+=256) cur[i] = 0u;
  if (t==0){ int run=0; for (int j=0;j<SB;++j){ bpre[j]=run; run+=bsum[j]; } }
  __syncthreads();

  if (b < SB){
    int pref = bpre[b];
    int i = b*1024 + t*4;
    if (i+0 < N) rowfin[i+0] = rowptr[i+0] + pref;
    if (i+1 < N) rowfin[i+1] = rowptr[i+1] + pref;
    if (i+2 < N) rowfin[i+2] = rowptr[i+2] + pref;
    if (i+3 < N) rowfin[i+3] = rowptr[i+3] + pref;
    if (b==0 && t==0) rowfin[N] = Etot;
  }

  const unsigned short* pb = pu + (size_t)c*NBINS;
  int e0 = c*chunk, e1 = e0+chunk; if (e1 > Etot) e1 = Etot;
  int e = e0 + t;
  for (; e + 768 < e1; e += 1024){
    int ea=e, eb=e+256, ec=e+512, ed=e+768;
    int d0,s0,d1,s1,d2,s2,d3,s3;
    if (ea<E){ d0=dstv[ea]; s0=srcv[ea]; } else { d0=ea-E; s0=d0; }
    if (eb<E){ d1=dstv[eb]; s1=srcv[eb]; } else { d1=eb-E; s1=d1; }
    if (ec<E){ d2=dstv[ec]; s2=srcv[ec]; } else { d2=ec-E; s2=d2; }
    if (ed<E){ d3=dstv[ed]; s3=srcv[ed]; } else { d3=ed-E; s3=d3; }
    int r0=d0-lo, r1=d1-lo, r2=d2-lo, r3=d3-lo;
    if (r0>=0 && r0<HBINS){
      int base0 = rowptr[d0] + bpre[d0>>10] + (int)pb[d0];
      unsigned int o0 = atomicAdd(&cur[r0>>1], (r0&1)?65536u:1u);
      csr_src[base0 + ((r0&1)?(int)(o0>>16):(int)(o0&0xffff))] = s0;
    }
    if (r1>=0 && r1<HBINS){
      int base1 = rowptr[d1] + bpre[d1>>10] + (int)pb[d1];
      unsigned int o1 = atomicAdd(&cur[r1>>1], (r1&1)?65536u:1u);
      csr_src[base1 + ((r1&1)?(int)(o1>>16):(int)(o1&0xffff))] = s1;
    }
    if (r2>=0 && r2<HBINS){
      int base2 = rowptr[d2] + bpre[d2>>10] + (int)pb[d2];
      unsigned int o2 = atomicAdd(&cur[r2>>1], (r2&1)?65536u:1u);
      csr_src[base2 + ((r2&1)?(int)(o2>>16):(int)(o2&0xffff))] = s2;
    }
    if (r3>=0 && r3<HBINS){
      int base3 = rowptr[d3] + bpre[d3>>10] + (int)pb[d3];
      unsigned int o3 = atomicAdd(&cur[r3>>1], (r3&1)?65536u:1u);
      csr_src[base3 + ((r3&1)?(int)(o3>>16):(int)(o3&0xffff))] = s3;
    }
  }
  for (; e < e1; e += 256){
    int d,s;
    if (e<E){ d=dstv[e]; s=srcv[e]; } else { d=e-E; s=d; }
    int r = d - lo;
    if (r>=0 && r<HBINS){
      int base = rowptr[d] + bpre[d>>10] + (int)pb[d];
      unsigned int o = atomicAdd(&cur[r>>1], (r&1)?65536u:1u);
      csr_src[base + ((r&1)?(int)(o>>16):(int)(o&0xffff))] = s;
    }
  }
}

// ---------------- K4: Layer-1 aggregation v4 (channel-sliced, XCD-L2-resident) ----------------
// Wave per (dst, head); head = blockIdx&7 -> round-robin puts each head on one
// XCD, whose h1[:,head] slice (3.2MB) fits the 4MiB L2. 16 lanes x 4B cover
// the 64B head slice; 4 edge-slots; 2 rounds unrolled = 8 row-gathers in
// flight. Weight (1 exp) recomputed per slice, broadcast across the 16-lane
// group. No LDS, low VGPR -> 32 waves/CU. Invalid slots: w=0 (exact no-op),
// s=0 fallback row is cache-hot.
__global__ __launch_bounds__(256) void k_agg1(const __half* __restrict__ h1,
    const float* __restrict__ a_src1, const float* __restrict__ a_dst1,
    const int* __restrict__ rowfin, const int* __restrict__ csr_src,
    const float* __restrict__ bias1, _Float16* __restrict__ h2f, int N)
{
  int b = blockIdx.x;
  int h = b & 7;                       // head slice; rides round-robin XCD map
  int dst = (b >> 3)*4 + (threadIdx.x >> 6);
  if (dst >= N) return;
  int lane = threadIdx.x & 63;
  int es = lane >> 4;                  // edge slot 0..3
  int ch = lane & 15;                  // channel-pair index (2 ch)

  float ad = a_dst1[(size_t)dst*8 + h];
  int beg = rowfin[dst], end = rowfin[dst+1];
  int deg = end - beg;

  const char* hb = (const char*)h1 + h*64 + ch*4;   // my 4B of the 64B slice
  float a0 = 0.f, a1 = 0.f, wsum = 0.f;

  int r8 = deg >> 3;                   // full 8-edge double-rounds
  int i = beg + es;
  for (int r = 0; r < r8; ++r, i += 8){
    int sA = csr_src[i];
    int sB = csr_src[i+4];
    float eA = a_src1[(size_t)sA*8 + h];
    float eB = a_src1[(size_t)sB*8 + h];
    __half2 pA = *(const __half2*)(hb + (size_t)sA*512);
    __half2 pB = *(const __half2*)(hb + (size_t)sB*512);
    float wA = __expf(lrelu(eA + ad));
    float wB = __expf(lrelu(eB + ad));
    float2 fA = __half22float2(pA);
    float2 fB = __half22float2(pB);
    wsum += wA + wB;
    a0 += wA*fA.x + wB*fB.x;
    a1 += wA*fA.y + wB*fB.y;
  }
  // tail: up to 7 edges (slot-predicated, w=0 exact no-op)
  if (i < end){
    bool v2b = (i+4 < end);
    int sA = csr_src[i];
    int sB = v2b ? csr_src[i+4] : 0;
    float eA = a_src1[(size_t)sA*8 + h];
    float eB = a_src1[(size_t)sB*8 + h];
    __half2 pA = *(const __half2*)(hb + (size_t)sA*512);
    __half2 pB = *(const __half2*)(hb + (size_t)sB*512);
    float wA = __expf(lrelu(eA + ad));
    float wB = v2b ? __expf(lrelu(eB + ad)) : 0.f;
    float2 fA = __half22float2(pA);
    float2 fB = __half22float2(pB);
    wsum += wA + wB;
    a0 += wA*fA.x + wB*fB.x;
    a1 += wA*fA.y + wB*fB.y;
  } else if (i+4 < end){ // unreachable (i<end fails => i+4<end fails); kept for clarity
  }

  // combine the 4 edge slots
  wsum += __shfl_xor(wsum, 16); wsum += __shfl_xor(wsum, 32);
  a0   += __shfl_xor(a0,   16); a0   += __shfl_xor(a0,   32);
  a1   += __shfl_xor(a1,   16); a1   += __shfl_xor(a1,   32);

  if (es == 0){
    float dinv = 1.f/(wsum + 1e-16f);
    const float2 bv = *(const float2*)(bias1 + h*32 + ch*2);
    float o0 = a0*dinv + bv.x;
    float o1 = a1*dinv + bv.y;
    o0 = o0 > 0.f ? o0 : __expf(o0)-1.f;
    o1 = o1 > 0.f ? o1 : __expf(o1)-1.f;
    __half2 ov;
    ov.x = __float2half(o0);
    ov.y = __float2half(o1);
    *(__half2*)((char*)h2f + (size_t)dst*512 + h*64 + ch*4) = ov;
  }
}

// ---------------- K5: GEMM2 (MFMA): hb(fp16) = h2f @ W2, + a_src2/a_dst2 ----------------
__global__ __launch_bounds__(256) void k_gemm2(const _Float16* __restrict__ h2f,
    const _Float16* __restrict__ W2t, const float* __restrict__ as2, const float* __restrict__ ad2,
    _Float16* __restrict__ hbh, float* __restrict__ a_src2, float* __restrict__ a_dst2, int N)
{
  int t = threadIdx.x, wv = t>>6, lane = t&63;
  int col = lane&15, q = lane>>4;
  int n0 = blockIdx.x*64 + wv*16;
  int am = n0 + col; if (am > N-1) am = N-1;

  const _Float16* arow = h2f + (size_t)am*256 + q*8;
  const _Float16* brow = W2t + (size_t)col*256 + q*8;
  f32x4 acc = (f32x4){0.f,0.f,0.f,0.f};
  #pragma unroll
  for (int ks=0; ks<8; ++ks){
    f16x8 a = *(const f16x8*)(arow + ks*32);
    f16x8 b = *(const f16x8*)(brow + ks*32);
    acc = __builtin_amdgcn_mfma_f32_16x16x32_f16(a, b, acc, 0,0,0);
  }

  float vs = as2[col], vd = ad2[col];
  #pragma unroll
  for (int r=0; r<4; ++r){
    int n = n0 + q*4 + r;
    float v = acc[r];
    float pa = v*vs, pd = v*vd;
    #pragma unroll
    for (int msk=8; msk>=1; msk>>=1){ pa += __shfl_xor(pa,msk); pd += __shfl_xor(pd,msk); }
    if (n < N){
      hbh[(size_t)n*16 + col] = (_Float16)v;
      if (col==0){ a_src2[n] = pa; a_dst2[n] = pd; }
    }
  }
}

// ---------------- K6: Layer-2 aggregation: wave per dst, 4 edge-groups x 16 ch ----------------
__global__ __launch_bounds__(256) void k_agg2(const __half* __restrict__ hbh,
    const float* __restrict__ a_src2, const float* __restrict__ a_dst2,
    const int* __restrict__ rowfin, const int* __restrict__ csr_src,
    const float* __restrict__ bias2, float* __restrict__ out, int N)
{
  int wave = (blockIdx.x*blockDim.x + threadIdx.x) >> 6;
  if (wave >= N) return;
  int lane = threadIdx.x & 63;
  int eg   = lane >> 4;
  int ch   = lane & 15;
  float ad = a_dst2[wave];
  int beg = rowfin[wave], end = rowfin[wave+1];
  float acc = 0.f, wsum = 0.f;
  int i = beg + eg;
  for (; i+4 < end; i+=8){
    int s0 = csr_src[i], s1 = csr_src[i+4];
    float e0 = a_src2[s0], e1 = a_src2[s1];
    float h0 = __half2float(hbh[(size_t)s0*16 + ch]);
    float h1v = __half2float(hbh[(size_t)s1*16 + ch]);
    float w0 = __expf(lrelu(e0 + ad)), w1 = __expf(lrelu(e1 + ad));
    wsum += w0 + w1;
    acc += w0*h0 + w1*h1v;
  }
  for (; i<end; i+=4){
    int s = csr_src[i];
    float w = __expf(lrelu(a_src2[s] + ad));
    wsum += w;
    acc += w * __half2float(hbh[(size_t)s*16 + ch]);
  }
  acc  += __shfl_xor(acc, 16);  acc  += __shfl_xor(acc, 32);
  wsum += __shfl_xor(wsum, 16); wsum += __shfl_xor(wsum, 32);
  if (eg == 0)
    out[(size_t)wave*16 + ch] = acc/(wsum + 1e-16f) + bias2[ch];
}

extern "C" void kernel_launch(void* const* d_in, const int* in_sizes, int n_in,
                              void* d_out, int out_size, void* d_ws, size_t ws_size,
                              hipStream_t stream)
{
  const float* x   = (const float*)d_in[0];
  const int*   ei  = (const int*)  d_in[1];
  const float* W1  = (const float*)d_in[2];
  const float* as1 = (const float*)d_in[3];
  const float* ad1 = (const float*)d_in[4];
  const float* b1  = (const float*)d_in[5];
  const float* W2  = (const float*)d_in[6];
  const float* as2 = (const float*)d_in[7];
  const float* ad2 = (const float*)d_in[8];
  const float* b2  = (const float*)d_in[9];
  float* out = (float*)d_out;

  const int N    = in_sizes[0] / 128;       // 50000
  const int E    = in_sizes[1] / 2;         // 800000
  const int Etot = E + N;
  const int* srcv = ei;
  const int* dstv = ei + E;
  const int chunk = (Etot + NC - 1) / NC;   // 6641 < 65536 (u16-field safe)
  const int SB    = (N + 1023) / 1024;      // 49 scan blocks
  const int TN    = (N + 63) / 64;          // 782 gemm1 tiles

  char* p = (char*)d_ws;
  auto alloc = [&](size_t bytes)->void* {
    void* r = (void*)p;
    p += (bytes + 255) & ~((size_t)255);
    return r;
  };
  _Float16* h1   = (_Float16*)alloc((size_t)N*256*sizeof(_Float16));   // node-major [N][256]
  _Float16* W1t  = (_Float16*)alloc((size_t)256*128*sizeof(_Float16));
  _Float16* h2f  = (_Float16*)alloc((size_t)N*256*sizeof(_Float16));
  _Float16* W2t  = (_Float16*)alloc((size_t)16*256*sizeof(_Float16));
  _Float16* hbh  = (_Float16*)alloc((size_t)N*16*sizeof(_Float16));
  float* a_src1  = (float*)alloc((size_t)N*8*sizeof(float));
  float* a_dst1  = (float*)alloc((size_t)N*8*sizeof(float));
  float* a_src2  = (float*)alloc((size_t)N*sizeof(float));
  float* a_dst2  = (float*)alloc((size_t)N*sizeof(float));
  int*   rowptr  = (int*)alloc((size_t)(N+1)*sizeof(int));
  int*   rowfin  = (int*)alloc((size_t)(N+1)*sizeof(int));
  int*   bsum    = (int*)alloc(256*sizeof(int));
  unsigned int* partial = (unsigned int*)alloc((size_t)NC*HBINS*sizeof(unsigned int)); // u16[NC][50000]
  int*   csr_src = (int*)alloc((size_t)Etot*sizeof(int));

  // K1: histogram (chunk x half, 256 blocks) + weight prep
  k_histW<<<dim3(NBK+129), dim3(256), 0, stream>>>(dstv, partial, E, Etot, chunk,
                                                   W1, W1t, W2, W2t);
  // K2: scanAB (batched prefetch; blocks 0..SB-1) + gemm1 (blocks SB..SB+TN-1)
  k_g1scan<<<dim3(SB + TN), dim3(256), 0, stream>>>(x, W1t, as1, ad1, h1,
      a_src1, a_dst1, (unsigned long long*)partial, rowptr, bsum, N, SB);
  // K3: scatter + rowfin finalize
  k_scatter3<<<dim3(NBK), dim3(256), 0, stream>>>(srcv, dstv, rowptr,
      (const unsigned short*)partial, bsum, csr_src, rowfin, E, Etot, chunk, SB, N);
  // K4: agg1 v4 (channel-sliced; 8 head-blocks per 4-dst group)
  k_agg1<<<dim3(8 * ((N + 3)/4)), dim3(256), 0, stream>>>((const __half*)h1, a_src1, a_dst1,
      rowfin, csr_src, b1, h2f, N);
  // K5: gemm2 (fp16 hb)
  k_gemm2<<<dim3((N + 63)/64), dim3(256), 0, stream>>>(h2f, W2t, as2, ad2, hbh, a_src2, a_dst2, N);
  // K6: agg2
  k_agg2<<<dim3((N + 3)/4), dim3(256), 0, stream>>>((const __half*)hbh, a_src2, a_dst2,
      rowfin, csr_src, b2, out, N);
}

// Round 6
// 366.941 us; speedup vs baseline: 1.0133x; 1.0133x over previous
//
#include <hip/hip_runtime.h>
#include <hip/hip_fp16.h>
#include <math.h>

// 2-layer GAT. N=50000, E=800000 (+N self loops), F=128, H=8, C=32, NCLS=16.
// R22: v4 failed because row-major h1 put each 64B head slice inside a 128B
// line shared with the neighbor head -> per-XCD line working set 6.4MB > 4MiB
// L2 -> thrash (FETCH 350MB). v5 fixes the LAYOUT: h1 stored HEAD-MAJOR
// h1h[h][n][32ch] (distinct 64B lines), a_src1/a_dst1 head-major too. agg1:
// wave per (dst,head), head=blockIdx&7 rides round-robin block->XCD map ->
// per-XCD resident set = 3.2MB h1h slice + 0.2 a_src + 0.2 rowfin < 4MiB L2.
// csr stream uses nontemporal loads (no L2 pollution). 8 edge-slots x 8
// lanes x uint2 (8B/lane), 2 rounds unrolled, clamped-addr w=0 predication.
// Predicted: agg1 FETCH 221->~60MB, dur 73->~35us. If FETCH stays high the
// XCD-affinity assumption is refuted -> revert to v2 roofline.
//   K1 histW | K2 scanAB+gemm1 | K3 scatter3+rowfin | K4 agg1 | K5 gemm2 | K6 agg2

#define NC    128          // edge chunks
#define NBK   256          // hist/scatter blocks = NC * 2 halves
#define NBINS 50000
#define HBINS 25000        // bins per half
#define NWH   12500        // packed u32 words per half (2 bins each)

typedef _Float16 f16x8 __attribute__((ext_vector_type(8)));
typedef _Float16 f16x4 __attribute__((ext_vector_type(4)));
typedef float    f32x4 __attribute__((ext_vector_type(4)));

__device__ __forceinline__ float lrelu(float v){ return v > 0.f ? v : 0.2f*v; }

// ---------------- K1: hist (packed u16, chunk x half) + weight prep ----------------
__global__ __launch_bounds__(256) void k_histW(const int* __restrict__ dstv,
    unsigned int* __restrict__ partial, int E, int Etot, int chunk,
    const float* __restrict__ W1, _Float16* __restrict__ W1t,
    const float* __restrict__ W2, _Float16* __restrict__ W2t)
{
  int b = blockIdx.x, t = threadIdx.x;
  if (b >= NBK){
    int b2 = b - NBK;
    if (b2 < 128){
      W1t[t*128 + b2] = (_Float16)W1[b2*256 + t];
    } else {
      for (int i=t; i<4096; i+=256){ int k=i&255, j=i>>8; W2t[j*256+k] = (_Float16)W2[k*16+j]; }
    }
    return;
  }
  __shared__ unsigned int cnt[NWH];         // 50 KB -> 2 blocks/CU
  int c = b >> 1, half = b & 1, lo = half*HBINS;
  for (int i=t; i<NWH; i+=256) cnt[i] = 0u;
  __syncthreads();
  int e0 = c*chunk, e1 = e0+chunk; if (e1 > Etot) e1 = Etot;
  int e = e0 + t;
  for (; e + 768 < e1; e += 1024){
    int ea=e, eb=e+256, ec=e+512, ed=e+768;
    int d0 = (ea<E)?dstv[ea]:(ea-E);
    int d1 = (eb<E)?dstv[eb]:(eb-E);
    int d2 = (ec<E)?dstv[ec]:(ec-E);
    int d3 = (ed<E)?dstv[ed]:(ed-E);
    int r0=d0-lo, r1=d1-lo, r2=d2-lo, r3=d3-lo;
    if (r0>=0 && r0<HBINS) atomicAdd(&cnt[r0>>1], (r0&1)?65536u:1u);
    if (r1>=0 && r1<HBINS) atomicAdd(&cnt[r1>>1], (r1&1)?65536u:1u);
    if (r2>=0 && r2<HBINS) atomicAdd(&cnt[r2>>1], (r2&1)?65536u:1u);
    if (r3>=0 && r3<HBINS) atomicAdd(&cnt[r3>>1], (r3&1)?65536u:1u);
  }
  for (; e < e1; e += 256){
    int d = (e<E)?dstv[e]:(e-E);
    int r = d - lo;
    if (r>=0 && r<HBINS) atomicAdd(&cnt[r>>1], (r&1)?65536u:1u);
  }
  __syncthreads();
  unsigned int* dp = partial + (size_t)c*HBINS + (size_t)half*NWH;
  for (int i=t; i<NWH; i+=256) dp[i] = cnt[i];
}

// ---------------- K2: scanAB (blocks 0..SB-1, batched prefetch) + GEMM1 tiles ----------------
__global__ __launch_bounds__(256) void k_g1scan(const float* __restrict__ x,
    const _Float16* __restrict__ W1t, const float* __restrict__ as1,
    const float* __restrict__ ad1, _Float16* __restrict__ h1,
    float* __restrict__ a_src1, float* __restrict__ a_dst1,
    unsigned long long* __restrict__ partial, int* __restrict__ rowptr,
    int* __restrict__ bsum, int N, int SB)
{
  __shared__ char smem[33792];
  int t = threadIdx.x;
  int b = blockIdx.x;

  if (b < SB){
    // ---- scanAB with explicit 16-deep load batching (breaks latency chain) ----
    int* lds = (int*)smem;
    int base = b*1024 + t*4;
    int r0=0, r1=0, r2=0, r3=0;
    if (base < N){
      unsigned long long* P = partial + (base >> 2);
      for (int cc0=0; cc0<NC; cc0+=16){
        unsigned long long v[16];
        #pragma unroll
        for (int j=0;j<16;++j) v[j] = P[(size_t)(cc0+j)*12500];   // 16 loads in flight
        #pragma unroll
        for (int j=0;j<16;++j){
          unsigned long long pref =  (unsigned long long)(r0 & 0xffff)
            | ((unsigned long long)(r1 & 0xffff) << 16)
            | ((unsigned long long)(r2 & 0xffff) << 32)
            | ((unsigned long long)(r3 & 0xffff) << 48);
          P[(size_t)(cc0+j)*12500] = pref;
          r0 += (int)( v[j]        & 0xffff);
          r1 += (int)((v[j] >> 16) & 0xffff);
          r2 += (int)((v[j] >> 32) & 0xffff);
          r3 += (int)((v[j] >> 48) & 0xffff);
        }
      }
    }
    int tot = r0+r1+r2+r3;
    lds[t] = tot; __syncthreads();
    for (int off=1; off<256; off<<=1){
      int add = (t>=off)?lds[t-off]:0;
      __syncthreads();
      lds[t] += add;
      __syncthreads();
    }
    int excl = lds[t] - tot;
    if (t==255) bsum[b] = lds[t];
    int run = excl;
    if (base+0<N){ rowptr[base+0]=run; run+=r0; }
    if (base+1<N){ rowptr[base+1]=run; run+=r1; }
    if (base+2<N){ rowptr[base+2]=run; run+=r2; }
    if (base+3<N){ rowptr[base+3]=run; }
    return;
  }

  // ---- GEMM1 (MFMA): h1 = x @ W1 -> fp16 (HEAD-MAJOR), + a_src1/a_dst1 (head-major) ----
  _Float16* As = (_Float16*)smem;           // [64 rows][136 halves] (272 B stride)
  int n0 = (b - SB)*64;

  #pragma unroll
  for (int it=0; it<8; ++it){
    int c = it*256 + t;
    int row = c >> 5;
    int c4  = c & 31;
    int gr = n0 + row; if (gr > N-1) gr = N-1;
    float4 v = *(const float4*)(x + (size_t)gr*128 + c4*4);
    _Float16* dp = As + row*136 + c4*4;
    dp[0]=(_Float16)v.x; dp[1]=(_Float16)v.y; dp[2]=(_Float16)v.z; dp[3]=(_Float16)v.w;
  }
  __syncthreads();

  int wv = t>>6, lane = t&63;
  int m = lane&15, q = lane>>4;
  int r0w = wv*16;

  f16x8 afr[4];
  #pragma unroll
  for (int ks=0; ks<4; ++ks)
    afr[ks] = *(const f16x8*)((const char*)As + (r0w+m)*272 + ks*64 + q*16);

  f32x4 acc[16];
  #pragma unroll
  for (int ct=0; ct<16; ++ct) acc[ct] = (f32x4){0.f,0.f,0.f,0.f};

  const char* bbase = (const char*)W1t;
  #pragma unroll
  for (int ct=0; ct<16; ++ct){
    const char* bp = bbase + (ct*16 + m)*256 + q*16;
    f16x8 b0 = *(const f16x8*)(bp);
    f16x8 b1 = *(const f16x8*)(bp+64);
    f16x8 b2 = *(const f16x8*)(bp+128);
    f16x8 b3 = *(const f16x8*)(bp+192);
    acc[ct] = __builtin_amdgcn_mfma_f32_16x16x32_f16(afr[0], b0, acc[ct],0,0,0);
    acc[ct] = __builtin_amdgcn_mfma_f32_16x16x32_f16(afr[1], b1, acc[ct],0,0,0);
    acc[ct] = __builtin_amdgcn_mfma_f32_16x16x32_f16(afr[2], b2, acc[ct],0,0,0);
    acc[ct] = __builtin_amdgcn_mfma_f32_16x16x32_f16(afr[3], b3, acc[ct],0,0,0);
  }
  __syncthreads();

  _Float16* Hs = (_Float16*)smem;           // [64][264] halves, 528B stride
  #pragma unroll
  for (int ct=0; ct<16; ++ct){
    #pragma unroll
    for (int r=0; r<4; ++r)
      Hs[(size_t)(r0w + q*4 + r)*264 + ct*16 + m] = (_Float16)acc[ct][r];
  }
  __syncthreads();

  // h1 head-major store: h1h[hd][node][32ch]; 8 lanes x 8B cover the 64B slice
  {
    int hd  = lane >> 3;
    int c8  = lane & 7;
    for (int r=0; r<16; ++r){
      int grow = n0 + r0w + r;
      if (grow < N){
        uint2 v = *(const uint2*)((const char*)Hs + (size_t)(r0w+r)*528 + lane*8);
        *(uint2*)((char*)h1 + ((size_t)hd*N + grow)*64 + c8*8) = v;
      }
    }
  }

  #pragma unroll
  for (int p=t; p<512; p+=256){
    int row = p>>3, hd = p&7;
    int grow = n0 + row;
    if (grow < N){
      const _Float16* hr = Hs + (size_t)row*264 + hd*32;
      float sa=0.f, sd=0.f;
      #pragma unroll
      for (int c=0; c<32; ++c){
        float hv = (float)hr[c];
        sa += hv * as1[hd*32+c];
        sd += hv * ad1[hd*32+c];
      }
      a_src1[(size_t)hd*N + grow] = sa;     // head-major
      a_dst1[(size_t)hd*N + grow] = sd;     // head-major
    }
  }
}

// ---------------- K3: scatter (chunk x half, LDS u16 cursors) + rowfin finalize ----------------
__global__ __launch_bounds__(256) void k_scatter3(const int* __restrict__ srcv,
    const int* __restrict__ dstv, const int* __restrict__ rowptr,
    const unsigned short* __restrict__ pu, const int* __restrict__ bsum,
    int* __restrict__ csr_src, int* __restrict__ rowfin,
    int E, int Etot, int chunk, int SB, int N)
{
  __shared__ unsigned int cur[NWH];         // 50 KB -> 2 blocks/CU
  __shared__ int bpre[64];
  int b = blockIdx.x, t = threadIdx.x;
  int c = b >> 1, half = b & 1, lo = half*HBINS;
  for (int i=t; i<NWH; i+=256) cur[i] = 0u;
  if (t==0){ int run=0; for (int j=0;j<SB;++j){ bpre[j]=run; run+=bsum[j]; } }
  __syncthreads();

  if (b < SB){
    int pref = bpre[b];
    int i = b*1024 + t*4;
    if (i+0 < N) rowfin[i+0] = rowptr[i+0] + pref;
    if (i+1 < N) rowfin[i+1] = rowptr[i+1] + pref;
    if (i+2 < N) rowfin[i+2] = rowptr[i+2] + pref;
    if (i+3 < N) rowfin[i+3] = rowptr[i+3] + pref;
    if (b==0 && t==0) rowfin[N] = Etot;
  }

  const unsigned short* pb = pu + (size_t)c*NBINS;
  int e0 = c*chunk, e1 = e0+chunk; if (e1 > Etot) e1 = Etot;
  int e = e0 + t;
  for (; e + 768 < e1; e += 1024){
    int ea=e, eb=e+256, ec=e+512, ed=e+768;
    int d0,s0,d1,s1,d2,s2,d3,s3;
    if (ea<E){ d0=dstv[ea]; s0=srcv[ea]; } else { d0=ea-E; s0=d0; }
    if (eb<E){ d1=dstv[eb]; s1=srcv[eb]; } else { d1=eb-E; s1=d1; }
    if (ec<E){ d2=dstv[ec]; s2=srcv[ec]; } else { d2=ec-E; s2=d2; }
    if (ed<E){ d3=dstv[ed]; s3=srcv[ed]; } else { d3=ed-E; s3=d3; }
    int r0=d0-lo, r1=d1-lo, r2=d2-lo, r3=d3-lo;
    if (r0>=0 && r0<HBINS){
      int base0 = rowptr[d0] + bpre[d0>>10] + (int)pb[d0];
      unsigned int o0 = atomicAdd(&cur[r0>>1], (r0&1)?65536u:1u);
      csr_src[base0 + ((r0&1)?(int)(o0>>16):(int)(o0&0xffff))] = s0;
    }
    if (r1>=0 && r1<HBINS){
      int base1 = rowptr[d1] + bpre[d1>>10] + (int)pb[d1];
      unsigned int o1 = atomicAdd(&cur[r1>>1], (r1&1)?65536u:1u);
      csr_src[base1 + ((r1&1)?(int)(o1>>16):(int)(o1&0xffff))] = s1;
    }
    if (r2>=0 && r2<HBINS){
      int base2 = rowptr[d2] + bpre[d2>>10] + (int)pb[d2];
      unsigned int o2 = atomicAdd(&cur[r2>>1], (r2&1)?65536u:1u);
      csr_src[base2 + ((r2&1)?(int)(o2>>16):(int)(o2&0xffff))] = s2;
    }
    if (r3>=0 && r3<HBINS){
      int base3 = rowptr[d3] + bpre[d3>>10] + (int)pb[d3];
      unsigned int o3 = atomicAdd(&cur[r3>>1], (r3&1)?65536u:1u);
      csr_src[base3 + ((r3&1)?(int)(o3>>16):(int)(o3&0xffff))] = s3;
    }
  }
  for (; e < e1; e += 256){
    int d,s;
    if (e<E){ d=dstv[e]; s=srcv[e]; } else { d=e-E; s=d; }
    int r = d - lo;
    if (r>=0 && r<HBINS){
      int base = rowptr[d] + bpre[d>>10] + (int)pb[d];
      unsigned int o = atomicAdd(&cur[r>>1], (r&1)?65536u:1u);
      csr_src[base + ((r&1)?(int)(o>>16):(int)(o&0xffff))] = s;
    }
  }
}

// ---------------- K4: Layer-1 aggregation v5 (head-major, XCD-L2-resident) ----------------
// Wave per (dst, head); head = blockIdx&7 -> round-robin block->XCD map pins
// each head's 3.2MB h1h slice (+0.2MB a_src1h, 0.2MB rowfin) to one XCD L2.
// Lane layout: slot = lane>>3 (8 edge slots), c8 = lane&7 (8B of 64B slice).
// 2 rounds unrolled (16 edges, 6 loads in flight). Clamped-address loads +
// w=0 predication (no divergence; beg always valid via self-loop). csr
// stream is nontemporal (no L2 pollution). No LDS, ~30 VGPR.
__global__ __launch_bounds__(256) void k_agg1(const __half* __restrict__ h1h,
    const float* __restrict__ a_src1h, const float* __restrict__ a_dst1h,
    const int* __restrict__ rowfin, const int* __restrict__ csr_src,
    const float* __restrict__ bias1, _Float16* __restrict__ h2f, int N)
{
  int g = blockIdx.x;
  int h = g & 7;                        // head slice; rides round-robin XCD map
  int dst = (g >> 3)*4 + (threadIdx.x >> 6);
  if (dst >= N) return;
  int lane = threadIdx.x & 63;
  int slot = lane >> 3;                 // edge slot 0..7
  int c8   = lane & 7;                  // 8B chunk of the 64B head slice

  float ad = a_dst1h[(size_t)h*N + dst];
  int beg = rowfin[dst], end = rowfin[dst+1];

  const char*  hb  = (const char*)h1h + ((size_t)h*N)*64 + c8*8;
  const float* asb = a_src1h + (size_t)h*N;

  float a0=0.f, a1=0.f, a2=0.f, a3=0.f, wsum=0.f;

  for (int i0 = beg; i0 < end; i0 += 16){
    int iA = i0 + slot;
    int iB = i0 + 8 + slot;
    int cA = iA < end ? iA : beg;       // clamp: beg valid (deg>=1, self loop)
    int cB = iB < end ? iB : beg;
    int sA = __builtin_nontemporal_load(csr_src + cA);
    int sB = __builtin_nontemporal_load(csr_src + cB);
    float eA = asb[sA];
    float eB = asb[sB];
    uint2 pA = *(const uint2*)(hb + (size_t)sA*64);
    uint2 pB = *(const uint2*)(hb + (size_t)sB*64);
    float wA = (iA < end) ? __expf(lrelu(eA + ad)) : 0.f;
    float wB = (iB < end) ? __expf(lrelu(eB + ad)) : 0.f;
    wsum += wA + wB;
    const __half2* qA = (const __half2*)&pA;
    const __half2* qB = (const __half2*)&pB;
    float2 fA0 = __half22float2(qA[0]), fA1 = __half22float2(qA[1]);
    float2 fB0 = __half22float2(qB[0]), fB1 = __half22float2(qB[1]);
    a0 += wA*fA0.x + wB*fB0.x;
    a1 += wA*fA0.y + wB*fB0.y;
    a2 += wA*fA1.x + wB*fB1.x;
    a3 += wA*fA1.y + wB*fB1.y;
  }

  // reduce over the 8 edge slots (lane bits 3,4,5)
  #pragma unroll
  for (int mk = 8; mk <= 32; mk <<= 1){
    wsum += __shfl_xor(wsum, mk);
    a0 += __shfl_xor(a0, mk); a1 += __shfl_xor(a1, mk);
    a2 += __shfl_xor(a2, mk); a3 += __shfl_xor(a3, mk);
  }

  if (slot == 0){
    float dinv = 1.f/(wsum + 1e-16f);
    const float4 bv = *(const float4*)(bias1 + h*32 + c8*4);
    float o0 = a0*dinv + bv.x;
    float o1 = a1*dinv + bv.y;
    float o2 = a2*dinv + bv.z;
    float o3 = a3*dinv + bv.w;
    o0 = o0 > 0.f ? o0 : __expf(o0)-1.f;
    o1 = o1 > 0.f ? o1 : __expf(o1)-1.f;
    o2 = o2 > 0.f ? o2 : __expf(o2)-1.f;
    o3 = o3 > 0.f ? o3 : __expf(o3)-1.f;
    f16x4 ov = { (_Float16)o0, (_Float16)o1, (_Float16)o2, (_Float16)o3 };
    *(f16x4*)((char*)h2f + (size_t)dst*512 + h*64 + c8*8) = ov;   // row-major h2f
  }
}

// ---------------- K5: GEMM2 (MFMA): hb(fp16) = h2f @ W2, + a_src2/a_dst2 ----------------
__global__ __launch_bounds__(256) void k_gemm2(const _Float16* __restrict__ h2f,
    const _Float16* __restrict__ W2t, const float* __restrict__ as2, const float* __restrict__ ad2,
    _Float16* __restrict__ hbh, float* __restrict__ a_src2, float* __restrict__ a_dst2, int N)
{
  int t = threadIdx.x, wv = t>>6, lane = t&63;
  int col = lane&15, q = lane>>4;
  int n0 = blockIdx.x*64 + wv*16;
  int am = n0 + col; if (am > N-1) am = N-1;

  const _Float16* arow = h2f + (size_t)am*256 + q*8;
  const _Float16* brow = W2t + (size_t)col*256 + q*8;
  f32x4 acc = (f32x4){0.f,0.f,0.f,0.f};
  #pragma unroll
  for (int ks=0; ks<8; ++ks){
    f16x8 a = *(const f16x8*)(arow + ks*32);
    f16x8 b = *(const f16x8*)(brow + ks*32);
    acc = __builtin_amdgcn_mfma_f32_16x16x32_f16(a, b, acc, 0,0,0);
  }

  float vs = as2[col], vd = ad2[col];
  #pragma unroll
  for (int r=0; r<4; ++r){
    int n = n0 + q*4 + r;
    float v = acc[r];
    float pa = v*vs, pd = v*vd;
    #pragma unroll
    for (int msk=8; msk>=1; msk>>=1){ pa += __shfl_xor(pa,msk); pd += __shfl_xor(pd,msk); }
    if (n < N){
      hbh[(size_t)n*16 + col] = (_Float16)v;
      if (col==0){ a_src2[n] = pa; a_dst2[n] = pd; }
    }
  }
}

// ---------------- K6: Layer-2 aggregation: wave per dst, 4 edge-groups x 16 ch ----------------
__global__ __launch_bounds__(256) void k_agg2(const __half* __restrict__ hbh,
    const float* __restrict__ a_src2, const float* __restrict__ a_dst2,
    const int* __restrict__ rowfin, const int* __restrict__ csr_src,
    const float* __restrict__ bias2, float* __restrict__ out, int N)
{
  int wave = (blockIdx.x*blockDim.x + threadIdx.x) >> 6;
  if (wave >= N) return;
  int lane = threadIdx.x & 63;
  int eg   = lane >> 4;
  int ch   = lane & 15;
  float ad = a_dst2[wave];
  int beg = rowfin[wave], end = rowfin[wave+1];
  float acc = 0.f, wsum = 0.f;
  int i = beg + eg;
  for (; i+4 < end; i+=8){
    int s0 = csr_src[i], s1 = csr_src[i+4];
    float e0 = a_src2[s0], e1 = a_src2[s1];
    float h0 = __half2float(hbh[(size_t)s0*16 + ch]);
    float h1v = __half2float(hbh[(size_t)s1*16 + ch]);
    float w0 = __expf(lrelu(e0 + ad)), w1 = __expf(lrelu(e1 + ad));
    wsum += w0 + w1;
    acc += w0*h0 + w1*h1v;
  }
  for (; i<end; i+=4){
    int s = csr_src[i];
    float w = __expf(lrelu(a_src2[s] + ad));
    wsum += w;
    acc += w * __half2float(hbh[(size_t)s*16 + ch]);
  }
  acc  += __shfl_xor(acc, 16);  acc  += __shfl_xor(acc, 32);
  wsum += __shfl_xor(wsum, 16); wsum += __shfl_xor(wsum, 32);
  if (eg == 0)
    out[(size_t)wave*16 + ch] = acc/(wsum + 1e-16f) + bias2[ch];
}

extern "C" void kernel_launch(void* const* d_in, const int* in_sizes, int n_in,
                              void* d_out, int out_size, void* d_ws, size_t ws_size,
                              hipStream_t stream)
{
  const float* x   = (const float*)d_in[0];
  const int*   ei  = (const int*)  d_in[1];
  const float* W1  = (const float*)d_in[2];
  const float* as1 = (const float*)d_in[3];
  const float* ad1 = (const float*)d_in[4];
  const float* b1  = (const float*)d_in[5];
  const float* W2  = (const float*)d_in[6];
  const float* as2 = (const float*)d_in[7];
  const float* ad2 = (const float*)d_in[8];
  const float* b2  = (const float*)d_in[9];
  float* out = (float*)d_out;

  const int N    = in_sizes[0] / 128;       // 50000
  const int E    = in_sizes[1] / 2;         // 800000
  const int Etot = E + N;
  const int* srcv = ei;
  const int* dstv = ei + E;
  const int chunk = (Etot + NC - 1) / NC;   // 6641 < 65536 (u16-field safe)
  const int SB    = (N + 1023) / 1024;      // 49 scan blocks
  const int TN    = (N + 63) / 64;          // 782 gemm1 tiles

  char* p = (char*)d_ws;
  auto alloc = [&](size_t bytes)->void* {
    void* r = (void*)p;
    p += (bytes + 255) & ~((size_t)255);
    return r;
  };
  _Float16* h1   = (_Float16*)alloc((size_t)N*256*sizeof(_Float16));   // HEAD-MAJOR [8][N][32]
  _Float16* W1t  = (_Float16*)alloc((size_t)256*128*sizeof(_Float16));
  _Float16* h2f  = (_Float16*)alloc((size_t)N*256*sizeof(_Float16));   // node-major [N][256]
  _Float16* W2t  = (_Float16*)alloc((size_t)16*256*sizeof(_Float16));
  _Float16* hbh  = (_Float16*)alloc((size_t)N*16*sizeof(_Float16));
  float* a_src1  = (float*)alloc((size_t)N*8*sizeof(float));           // HEAD-MAJOR [8][N]
  float* a_dst1  = (float*)alloc((size_t)N*8*sizeof(float));           // HEAD-MAJOR [8][N]
  float* a_src2  = (float*)alloc((size_t)N*sizeof(float));
  float* a_dst2  = (float*)alloc((size_t)N*sizeof(float));
  int*   rowptr  = (int*)alloc((size_t)(N+1)*sizeof(int));
  int*   rowfin  = (int*)alloc((size_t)(N+1)*sizeof(int));
  int*   bsum    = (int*)alloc(256*sizeof(int));
  unsigned int* partial = (unsigned int*)alloc((size_t)NC*HBINS*sizeof(unsigned int)); // u16[NC][50000]
  int*   csr_src = (int*)alloc((size_t)Etot*sizeof(int));

  // K1: histogram (chunk x half, 256 blocks) + weight prep
  k_histW<<<dim3(NBK+129), dim3(256), 0, stream>>>(dstv, partial, E, Etot, chunk,
                                                   W1, W1t, W2, W2t);
  // K2: scanAB (batched prefetch; blocks 0..SB-1) + gemm1 (blocks SB..SB+TN-1)
  k_g1scan<<<dim3(SB + TN), dim3(256), 0, stream>>>(x, W1t, as1, ad1, h1,
      a_src1, a_dst1, (unsigned long long*)partial, rowptr, bsum, N, SB);
  // K3: scatter + rowfin finalize
  k_scatter3<<<dim3(NBK), dim3(256), 0, stream>>>(srcv, dstv, rowptr,
      (const unsigned short*)partial, bsum, csr_src, rowfin, E, Etot, chunk, SB, N);
  // K4: agg1 v5 (head-major, 8 head-blocks interleaved for XCD affinity)
  k_agg1<<<dim3(8 * ((N + 3)/4)), dim3(256), 0, stream>>>((const __half*)h1, a_src1, a_dst1,
      rowfin, csr_src, b1, h2f, N);
  // K5: gemm2 (fp16 hb)
  k_gemm2<<<dim3((N + 63)/64), dim3(256), 0, stream>>>(h2f, W2t, as2, ad2, hbh, a_src2, a_dst2, N);
  // K6: agg2
  k_agg2<<<dim3((N + 3)/4), dim3(256), 0, stream>>>((const __half*)hbh, a_src2, a_dst2,
      rowfin, csr_src, b2, out, N);
}

// Round 7
// 320.535 us; speedup vs baseline: 1.1600x; 1.1448x over previous
//
#include <hip/hip_runtime.h>
#include <hip/hip_fp16.h>
#include <math.h>

// 2-layer GAT. N=50000, E=800000 (+N self loops), F=128, H=8, C=32, NCLS=16.
// R23: agg1 CLOSED at ~73us (v2): three structures bracket it -- v2 is at the
// ~6TB/s VGPR-delivery floor (435MB compulsory = 850K edges x 512B row);
// v5 (R22) proved L2-residency (FETCH 221->39MB) doesn't beat it (175us,
// 8x wave overhead). v2 restored verbatim. This round: CSR build replaced
// with atomic counting-sort -- the old hist(12.8MB RMW x2) + scan(25.6MB RMW)
// + pb-gather(12.8MB) existed only to avoid global atomics, but the LDS
// scatter was ALREADY order-nondeterministic within segments (absmax
// bit-stable 2^-9 across 6 kernels -> fp16 quanta dominate). New: deg
// atomics (200KB L2-resident) -> scan reads deg directly -> scatter via
// rowptr[d]+bpre+atomicAdd(cur[d]).
//   K1 prep(Wt,deg=1,cur=0) | K2 deg | K3 scan+gemm1 | K4 scatter | K5 agg1
//   | K6 gemm2 | K7 agg2

typedef _Float16 f16x8 __attribute__((ext_vector_type(8)));
typedef _Float16 f16x4 __attribute__((ext_vector_type(4)));
typedef float    f32x4 __attribute__((ext_vector_type(4)));

__device__ __forceinline__ float lrelu(float v){ return v > 0.f ? v : 0.2f*v; }

// ---------------- K1: weight prep + deg=1 (self loops) + cur=0 ----------------
__global__ __launch_bounds__(256) void k_prep(const float* __restrict__ W1,
    _Float16* __restrict__ W1t, const float* __restrict__ W2,
    _Float16* __restrict__ W2t, int* __restrict__ deg, int* __restrict__ cur, int N)
{
  int b = blockIdx.x, t = threadIdx.x;
  if (b < 128){
    W1t[t*128 + b] = (_Float16)W1[b*256 + t];
  } else if (b == 128){
    for (int i=t; i<4096; i+=256){ int k=i&255, j=i>>8; W2t[j*256+k] = (_Float16)W2[k*16+j]; }
  } else {
    int i = (b-129)*1024 + t*4;
    if (i+0 < N){ deg[i+0] = 1; cur[i+0] = 0; }
    if (i+1 < N){ deg[i+1] = 1; cur[i+1] = 0; }
    if (i+2 < N){ deg[i+2] = 1; cur[i+2] = 0; }
    if (i+3 < N){ deg[i+3] = 1; cur[i+3] = 0; }
  }
}

// ---------------- K2: degree count via global atomics (L2-resident 200KB) ----------------
__global__ __launch_bounds__(256) void k_deg(const int* __restrict__ dstv,
    int* __restrict__ deg, int E)
{
  int e = blockIdx.x*1024 + threadIdx.x*4;
  if (e+3 < E){
    int4 d = *(const int4*)(dstv + e);
    atomicAdd(&deg[d.x], 1);
    atomicAdd(&deg[d.y], 1);
    atomicAdd(&deg[d.z], 1);
    atomicAdd(&deg[d.w], 1);
  } else {
    for (int i=e; i<E; ++i) atomicAdd(&deg[dstv[i]], 1);
  }
}

// ---------------- K3: scan(deg) (blocks 0..SB-1) + GEMM1 tiles ----------------
__global__ __launch_bounds__(256) void k_g1scan(const float* __restrict__ x,
    const _Float16* __restrict__ W1t, const float* __restrict__ as1,
    const float* __restrict__ ad1, _Float16* __restrict__ h1,
    float* __restrict__ a_src1, float* __restrict__ a_dst1,
    const int* __restrict__ deg, int* __restrict__ rowptr,
    int* __restrict__ bsum, int N, int SB)
{
  __shared__ char smem[33792];
  int t = threadIdx.x;
  int b = blockIdx.x;

  if (b < SB){
    // ---- block-local exclusive scan over deg (N%4==0 -> int4 safe) ----
    int* lds = (int*)smem;
    int base = b*1024 + t*4;
    int r0=0, r1=0, r2=0, r3=0;
    if (base < N){
      int4 dv = *(const int4*)(deg + base);
      r0=dv.x; r1=dv.y; r2=dv.z; r3=dv.w;
    }
    int tot = r0+r1+r2+r3;
    lds[t] = tot; __syncthreads();
    for (int off=1; off<256; off<<=1){
      int add = (t>=off)?lds[t-off]:0;
      __syncthreads();
      lds[t] += add;
      __syncthreads();
    }
    int excl = lds[t] - tot;
    if (t==255) bsum[b] = lds[t];
    int run = excl;
    if (base+0<N){ rowptr[base+0]=run; run+=r0; }
    if (base+1<N){ rowptr[base+1]=run; run+=r1; }
    if (base+2<N){ rowptr[base+2]=run; run+=r2; }
    if (base+3<N){ rowptr[base+3]=run; }
    return;
  }

  // ---- GEMM1 (MFMA): h1 = x @ W1 -> fp16 (node-major), + a_src1/a_dst1 ----
  _Float16* As = (_Float16*)smem;           // [64 rows][136 halves] (272 B stride)
  int n0 = (b - SB)*64;

  #pragma unroll
  for (int it=0; it<8; ++it){
    int c = it*256 + t;
    int row = c >> 5;
    int c4  = c & 31;
    int gr = n0 + row; if (gr > N-1) gr = N-1;
    float4 v = *(const float4*)(x + (size_t)gr*128 + c4*4);
    _Float16* dp = As + row*136 + c4*4;
    dp[0]=(_Float16)v.x; dp[1]=(_Float16)v.y; dp[2]=(_Float16)v.z; dp[3]=(_Float16)v.w;
  }
  __syncthreads();

  int wv = t>>6, lane = t&63;
  int m = lane&15, q = lane>>4;
  int r0w = wv*16;

  f16x8 afr[4];
  #pragma unroll
  for (int ks=0; ks<4; ++ks)
    afr[ks] = *(const f16x8*)((const char*)As + (r0w+m)*272 + ks*64 + q*16);

  f32x4 acc[16];
  #pragma unroll
  for (int ct=0; ct<16; ++ct) acc[ct] = (f32x4){0.f,0.f,0.f,0.f};

  const char* bbase = (const char*)W1t;
  #pragma unroll
  for (int ct=0; ct<16; ++ct){
    const char* bp = bbase + (ct*16 + m)*256 + q*16;
    f16x8 b0 = *(const f16x8*)(bp);
    f16x8 b1 = *(const f16x8*)(bp+64);
    f16x8 b2 = *(const f16x8*)(bp+128);
    f16x8 b3 = *(const f16x8*)(bp+192);
    acc[ct] = __builtin_amdgcn_mfma_f32_16x16x32_f16(afr[0], b0, acc[ct],0,0,0);
    acc[ct] = __builtin_amdgcn_mfma_f32_16x16x32_f16(afr[1], b1, acc[ct],0,0,0);
    acc[ct] = __builtin_amdgcn_mfma_f32_16x16x32_f16(afr[2], b2, acc[ct],0,0,0);
    acc[ct] = __builtin_amdgcn_mfma_f32_16x16x32_f16(afr[3], b3, acc[ct],0,0,0);
  }
  __syncthreads();

  _Float16* Hs = (_Float16*)smem;           // [64][264] halves, 528B stride
  #pragma unroll
  for (int ct=0; ct<16; ++ct){
    #pragma unroll
    for (int r=0; r<4; ++r)
      Hs[(size_t)(r0w + q*4 + r)*264 + ct*16 + m] = (_Float16)acc[ct][r];
  }
  __syncthreads();

  for (int r=0; r<16; ++r){
    int grow = n0 + r0w + r;
    if (grow < N){
      uint2 v = *(const uint2*)((const char*)Hs + (size_t)(r0w+r)*528 + lane*8);
      *(uint2*)((char*)h1 + (size_t)grow*512 + lane*8) = v;
    }
  }

  #pragma unroll
  for (int p=t; p<512; p+=256){
    int row = p>>3, hd = p&7;
    int grow = n0 + row;
    if (grow < N){
      const _Float16* hr = Hs + (size_t)row*264 + hd*32;
      float sa=0.f, sd=0.f;
      #pragma unroll
      for (int c=0; c<32; ++c){
        float hv = (float)hr[c];
        sa += hv * as1[hd*32+c];
        sd += hv * ad1[hd*32+c];
      }
      a_src1[(size_t)grow*8+hd] = sa;
      a_dst1[(size_t)grow*8+hd] = sd;
    }
  }
}

// ---------------- K4: scatter via global cursor atomics + rowfin finalize ----------------
__global__ __launch_bounds__(256) void k_scatter(const int* __restrict__ srcv,
    const int* __restrict__ dstv, const int* __restrict__ rowptr,
    const int* __restrict__ bsum, int* __restrict__ cur,
    int* __restrict__ csr_src, int* __restrict__ rowfin,
    int E, int Etot, int chunk, int SB, int N)
{
  __shared__ int bpre[64];
  int b = blockIdx.x, t = threadIdx.x;
  if (t==0){ int run=0; for (int j=0;j<SB;++j){ bpre[j]=run; run+=bsum[j]; } }
  __syncthreads();

  if (b < SB){
    int pref = bpre[b];
    int i = b*1024 + t*4;
    if (i+0 < N) rowfin[i+0] = rowptr[i+0] + pref;
    if (i+1 < N) rowfin[i+1] = rowptr[i+1] + pref;
    if (i+2 < N) rowfin[i+2] = rowptr[i+2] + pref;
    if (i+3 < N) rowfin[i+3] = rowptr[i+3] + pref;
    if (b==0 && t==0) rowfin[N] = Etot;
  }

  int e0 = b*chunk, e1 = e0+chunk; if (e1 > Etot) e1 = Etot;
  int e = e0 + t;
  for (; e + 768 < e1; e += 1024){
    int ea=e, eb=e+256, ec=e+512, ed=e+768;
    int d0,s0,d1,s1,d2,s2,d3,s3;
    if (ea<E){ d0=dstv[ea]; s0=srcv[ea]; } else { d0=ea-E; s0=d0; }
    if (eb<E){ d1=dstv[eb]; s1=srcv[eb]; } else { d1=eb-E; s1=d1; }
    if (ec<E){ d2=dstv[ec]; s2=srcv[ec]; } else { d2=ec-E; s2=d2; }
    if (ed<E){ d3=dstv[ed]; s3=srcv[ed]; } else { d3=ed-E; s3=d3; }
    int b0 = rowptr[d0] + bpre[d0>>10];
    int b1 = rowptr[d1] + bpre[d1>>10];
    int b2 = rowptr[d2] + bpre[d2>>10];
    int b3 = rowptr[d3] + bpre[d3>>10];
    int o0 = atomicAdd(&cur[d0], 1);
    int o1 = atomicAdd(&cur[d1], 1);
    int o2 = atomicAdd(&cur[d2], 1);
    int o3 = atomicAdd(&cur[d3], 1);
    csr_src[b0 + o0] = s0;
    csr_src[b1 + o1] = s1;
    csr_src[b2 + o2] = s2;
    csr_src[b3 + o3] = s3;
  }
  for (; e < e1; e += 256){
    int d,s;
    if (e<E){ d=dstv[e]; s=srcv[e]; } else { d=e-E; s=d; }
    int base = rowptr[d] + bpre[d>>10];
    int o = atomicAdd(&cur[d], 1);
    csr_src[base + o] = s;
  }
}

// ---------------- K5: Layer-1 aggregation v2 (two-phase, 16-deep scalar-addr gathers) ----------------
// Verified 73us; at the ~6TB/s VGPR-delivery floor (bytes compulsory).
__global__ __launch_bounds__(256) void k_agg1(const __half* __restrict__ h1,
    const float* __restrict__ a_src1, const float* __restrict__ a_dst1,
    const int* __restrict__ rowfin, const int* __restrict__ csr_src,
    const float* __restrict__ bias1, _Float16* __restrict__ h2f, int N)
{
  __shared__ float wlds[4*640];             // 4 waves x (64 edges x 9 floats, pad)
  int wave = (blockIdx.x*blockDim.x + threadIdx.x) >> 6;
  if (wave >= N) return;
  int lane = threadIdx.x & 63;
  int wid  = (threadIdx.x >> 6) & 3;
  int head = lane >> 3;
  float* wb = wlds + wid*640;
  const float* wcol = wb + head;            // + j*9 per edge

  int beg = rowfin[wave], end = rowfin[wave+1];
  int deg = end - beg;
  const float4 av0 = *(const float4*)(a_dst1 + (size_t)wave*8);
  const float4 av1 = *(const float4*)(a_dst1 + (size_t)wave*8 + 4);

  float4 acc = make_float4(0.f,0.f,0.f,0.f);
  float wsum = 0.f;

  for (int kb = 0; kb < deg; kb += 64){
    int nb = deg - kb; if (nb > 64) nb = 64;

    // ---- phase A: per-lane edge weights for all 8 heads ----
    int sl = 0;
    if (lane < nb) sl = csr_src[beg + kb + lane];
    const float4* ep = (const float4*)(a_src1 + (size_t)sl*8);
    float4 e0 = ep[0];
    float4 e1 = ep[1];
    float w0=0.f,w1=0.f,w2=0.f,w3=0.f,w4=0.f,w5=0.f,w6=0.f,w7=0.f;
    if (lane < nb){
      w0 = __expf(lrelu(e0.x + av0.x));
      w1 = __expf(lrelu(e0.y + av0.y));
      w2 = __expf(lrelu(e0.z + av0.z));
      w3 = __expf(lrelu(e0.w + av0.w));
      w4 = __expf(lrelu(e1.x + av1.x));
      w5 = __expf(lrelu(e1.y + av1.y));
      w6 = __expf(lrelu(e1.z + av1.z));
      w7 = __expf(lrelu(e1.w + av1.w));
    }
    float* wr = wb + lane*9;
    wr[0]=w0; wr[1]=w1; wr[2]=w2; wr[3]=w3;
    wr[4]=w4; wr[5]=w5; wr[6]=w6; wr[7]=w7;
    // no barrier: region is per-wave private; same-wave DS ops are ordered.

    // ---- phase B: 16-deep gather batches ----
    int nb16 = nb & ~15;
    int j = 0;
    for (; j < nb16; j += 16){
      uint2 p[16];
      #pragma unroll
      for (int u=0;u<16;++u){
        int s = __builtin_amdgcn_readlane(sl, j+u);       // scalar row base
        p[u] = *(const uint2*)((const char*)h1 + (size_t)s*512 + lane*8);
      }
      float wv[16];
      #pragma unroll
      for (int u=0;u<16;++u) wv[u] = wcol[(j+u)*9];
      #pragma unroll
      for (int u=0;u<16;++u){
        wsum += wv[u];
        const __half2* qq = (const __half2*)&p[u];
        float2 f0 = __half22float2(qq[0]);
        float2 f1 = __half22float2(qq[1]);
        acc.x += wv[u]*f0.x; acc.y += wv[u]*f0.y;
        acc.z += wv[u]*f1.x; acc.w += wv[u]*f1.y;
      }
    }
    // remainder: padded 4-batches; padded slots have w==0 (exact no-op)
    for (; j < nb; j += 4){
      uint2 p[4]; float wv[4];
      #pragma unroll
      for (int u=0;u<4;++u){
        int jj = j+u;
        int s = __builtin_amdgcn_readlane(sl, jj & 63);
        p[u] = *(const uint2*)((const char*)h1 + (size_t)s*512 + lane*8);
        wv[u] = (jj < 64) ? wcol[jj*9] : 0.f;
      }
      #pragma unroll
      for (int u=0;u<4;++u){
        wsum += wv[u];
        const __half2* qq = (const __half2*)&p[u];
        float2 f0 = __half22float2(qq[0]);
        float2 f1 = __half22float2(qq[1]);
        acc.x += wv[u]*f0.x; acc.y += wv[u]*f0.y;
        acc.z += wv[u]*f1.x; acc.w += wv[u]*f1.y;
      }
    }
  }

  float dinv = 1.f/(wsum + 1e-16f);
  const float4 bv = *(const float4*)(bias1 + lane*4);
  float4 o;
  o.x = acc.x*dinv + bv.x;
  o.y = acc.y*dinv + bv.y;
  o.z = acc.z*dinv + bv.z;
  o.w = acc.w*dinv + bv.w;
  o.x = o.x > 0.f ? o.x : __expf(o.x)-1.f;
  o.y = o.y > 0.f ? o.y : __expf(o.y)-1.f;
  o.z = o.z > 0.f ? o.z : __expf(o.z)-1.f;
  o.w = o.w > 0.f ? o.w : __expf(o.w)-1.f;
  f16x4 ov = { (_Float16)o.x, (_Float16)o.y, (_Float16)o.z, (_Float16)o.w };
  *(f16x4*)(h2f + (size_t)wave*256 + lane*4) = ov;
}

// ---------------- K6: GEMM2 (MFMA): hb(fp16) = h2f @ W2, + a_src2/a_dst2 ----------------
__global__ __launch_bounds__(256) void k_gemm2(const _Float16* __restrict__ h2f,
    const _Float16* __restrict__ W2t, const float* __restrict__ as2, const float* __restrict__ ad2,
    _Float16* __restrict__ hbh, float* __restrict__ a_src2, float* __restrict__ a_dst2, int N)
{
  int t = threadIdx.x, wv = t>>6, lane = t&63;
  int col = lane&15, q = lane>>4;
  int n0 = blockIdx.x*64 + wv*16;
  int am = n0 + col; if (am > N-1) am = N-1;

  const _Float16* arow = h2f + (size_t)am*256 + q*8;
  const _Float16* brow = W2t + (size_t)col*256 + q*8;
  f32x4 acc = (f32x4){0.f,0.f,0.f,0.f};
  #pragma unroll
  for (int ks=0; ks<8; ++ks){
    f16x8 a = *(const f16x8*)(arow + ks*32);
    f16x8 b = *(const f16x8*)(brow + ks*32);
    acc = __builtin_amdgcn_mfma_f32_16x16x32_f16(a, b, acc, 0,0,0);
  }

  float vs = as2[col], vd = ad2[col];
  #pragma unroll
  for (int r=0; r<4; ++r){
    int n = n0 + q*4 + r;
    float v = acc[r];
    float pa = v*vs, pd = v*vd;
    #pragma unroll
    for (int msk=8; msk>=1; msk>>=1){ pa += __shfl_xor(pa,msk); pd += __shfl_xor(pd,msk); }
    if (n < N){
      hbh[(size_t)n*16 + col] = (_Float16)v;
      if (col==0){ a_src2[n] = pa; a_dst2[n] = pd; }
    }
  }
}

// ---------------- K7: Layer-2 aggregation: wave per dst, 4 edge-groups x 16 ch ----------------
__global__ __launch_bounds__(256) void k_agg2(const __half* __restrict__ hbh,
    const float* __restrict__ a_src2, const float* __restrict__ a_dst2,
    const int* __restrict__ rowfin, const int* __restrict__ csr_src,
    const float* __restrict__ bias2, float* __restrict__ out, int N)
{
  int wave = (blockIdx.x*blockDim.x + threadIdx.x) >> 6;
  if (wave >= N) return;
  int lane = threadIdx.x & 63;
  int eg   = lane >> 4;
  int ch   = lane & 15;
  float ad = a_dst2[wave];
  int beg = rowfin[wave], end = rowfin[wave+1];
  float acc = 0.f, wsum = 0.f;
  int i = beg + eg;
  for (; i+4 < end; i+=8){
    int s0 = csr_src[i], s1 = csr_src[i+4];
    float e0 = a_src2[s0], e1 = a_src2[s1];
    float h0 = __half2float(hbh[(size_t)s0*16 + ch]);
    float h1v = __half2float(hbh[(size_t)s1*16 + ch]);
    float w0 = __expf(lrelu(e0 + ad)), w1 = __expf(lrelu(e1 + ad));
    wsum += w0 + w1;
    acc += w0*h0 + w1*h1v;
  }
  for (; i<end; i+=4){
    int s = csr_src[i];
    float w = __expf(lrelu(a_src2[s] + ad));
    wsum += w;
    acc += w * __half2float(hbh[(size_t)s*16 + ch]);
  }
  acc  += __shfl_xor(acc, 16);  acc  += __shfl_xor(acc, 32);
  wsum += __shfl_xor(wsum, 16); wsum += __shfl_xor(wsum, 32);
  if (eg == 0)
    out[(size_t)wave*16 + ch] = acc/(wsum + 1e-16f) + bias2[ch];
}

extern "C" void kernel_launch(void* const* d_in, const int* in_sizes, int n_in,
                              void* d_out, int out_size, void* d_ws, size_t ws_size,
                              hipStream_t stream)
{
  const float* x   = (const float*)d_in[0];
  const int*   ei  = (const int*)  d_in[1];
  const float* W1  = (const float*)d_in[2];
  const float* as1 = (const float*)d_in[3];
  const float* ad1 = (const float*)d_in[4];
  const float* b1  = (const float*)d_in[5];
  const float* W2  = (const float*)d_in[6];
  const float* as2 = (const float*)d_in[7];
  const float* ad2 = (const float*)d_in[8];
  const float* b2  = (const float*)d_in[9];
  float* out = (float*)d_out;

  const int N    = in_sizes[0] / 128;       // 50000
  const int E    = in_sizes[1] / 2;         // 800000
  const int Etot = E + N;
  const int* srcv = ei;
  const int* dstv = ei + E;
  const int SB    = (N + 1023) / 1024;      // 49 scan blocks
  const int TN    = (N + 63) / 64;          // 782 gemm1 tiles
  const int ZB    = (N + 1023) / 1024;      // 49 init blocks
  const int DB    = (E + 1023) / 1024;      // 782 deg blocks
  const int chunk = (Etot + 255) / 256;     // scatter chunk per block

  char* p = (char*)d_ws;
  auto alloc = [&](size_t bytes)->void* {
    void* r = (void*)p;
    p += (bytes + 255) & ~((size_t)255);
    return r;
  };
  _Float16* h1   = (_Float16*)alloc((size_t)N*256*sizeof(_Float16));   // node-major [N][256]
  _Float16* W1t  = (_Float16*)alloc((size_t)256*128*sizeof(_Float16));
  _Float16* h2f  = (_Float16*)alloc((size_t)N*256*sizeof(_Float16));
  _Float16* W2t  = (_Float16*)alloc((size_t)16*256*sizeof(_Float16));
  _Float16* hbh  = (_Float16*)alloc((size_t)N*16*sizeof(_Float16));
  float* a_src1  = (float*)alloc((size_t)N*8*sizeof(float));
  float* a_dst1  = (float*)alloc((size_t)N*8*sizeof(float));
  float* a_src2  = (float*)alloc((size_t)N*sizeof(float));
  float* a_dst2  = (float*)alloc((size_t)N*sizeof(float));
  int*   rowptr  = (int*)alloc((size_t)(N+1)*sizeof(int));
  int*   rowfin  = (int*)alloc((size_t)(N+1)*sizeof(int));
  int*   bsum    = (int*)alloc(256*sizeof(int));
  int*   deg     = (int*)alloc((size_t)N*sizeof(int));
  int*   cur     = (int*)alloc((size_t)N*sizeof(int));
  int*   csr_src = (int*)alloc((size_t)Etot*sizeof(int));

  // K1: W transposes + deg=1 (covers self loops) + cur=0
  k_prep<<<dim3(129 + ZB), dim3(256), 0, stream>>>(W1, W1t, W2, W2t, deg, cur, N);
  // K2: degree histogram via global atomics (deg is 200KB, L2-resident)
  k_deg<<<dim3(DB), dim3(256), 0, stream>>>(dstv, deg, E);
  // K3: scan(deg) (blocks 0..SB-1) + gemm1 (blocks SB..SB+TN-1)
  k_g1scan<<<dim3(SB + TN), dim3(256), 0, stream>>>(x, W1t, as1, ad1, h1,
      a_src1, a_dst1, deg, rowptr, bsum, N, SB);
  // K4: scatter via global cursor atomics + rowfin finalize
  k_scatter<<<dim3(256), dim3(256), 0, stream>>>(srcv, dstv, rowptr, bsum, cur,
      csr_src, rowfin, E, Etot, chunk, SB, N);
  // K5: agg1 (v2, verified 73us roofline)
  k_agg1<<<dim3((N + 3)/4), dim3(256), 0, stream>>>((const __half*)h1, a_src1, a_dst1,
      rowfin, csr_src, b1, h2f, N);
  // K6: gemm2 (fp16 hb)
  k_gemm2<<<dim3((N + 63)/64), dim3(256), 0, stream>>>(h2f, W2t, as2, ad2, hbh, a_src2, a_dst2, N);
  // K7: agg2
  k_agg2<<<dim3((N + 3)/4), dim3(256), 0, stream>>>((const __half*)hbh, a_src2, a_dst2,
      rowfin, csr_src, b2, out, N);
}